// Round 4
// baseline (6248.721 us; speedup 1.0000x reference)
//
#include <hip/hip_runtime.h>
#include <stdint.h>

// BayesLSTM R3: persistent kernel with HAND-ROLLED grid barrier (no
// cooperative API — R2 showed hipLaunchCooperativeKernel never ran here).
// 256 blocks (= #CUs, all co-resident), 129 barrier-separated stages.
// Stage t: layer0 blocks (0..127) do step t, layer1 blocks (128..255) do
// step t-1. Each block owns 2 output columns x 4 gate slices, samples its
// 8 x Ktot weight stripe straight into LDS (threefry keys from a
// prologue-built table in ws), chunked LDS GEMM (k-split 16), reduce +
// activate. Sampled weights never touch global memory.

typedef unsigned int u32;

#define Bn 64
#define Tn 128
#define INn 64
#define Hn 256
#define Gn 1024
#define BH (Bn * Hn)

#define OFF_ELV_WIH0 0
#define OFF_ELV_WHH0 65536
#define OFF_ELV_WIH1 327680
#define OFF_ELV_WHH1 589824
#define OFF_ELV_B    851968            // bih0,bhh0,bih1,bhh1 (4*1024)
#define OFF_RING     856064
#define OFF_H0       (OFF_RING + 2 * BH)
#define OFF_H1       (OFF_H0 + 2 * BH)
#define OFF_C0       (OFF_H1 + 2 * BH)
#define OFF_C1       (OFF_C0 + BH)
#define OFF_KEYS     (OFF_C1 + BH)     // 2*128*8 u32 key table
#define OFF_BAR      (OFF_KEYS + 2 * Tn * 8)
#define WS_FLOATS    (OFF_BAR + 16)    // 989200 floats = 3.96 MiB
#define STATE_FLOATS (OFF_KEYS - OFF_RING)
#define OUT_HN       (Bn * Tn * Hn)

struct KP { u32 a, b; };

// Threefry-2x32, 20 rounds — matches jax/_src/prng.py exactly.
__device__ __forceinline__ KP tf(u32 k0, u32 k1, u32 x0, u32 x1) {
  u32 ks2 = k0 ^ k1 ^ 0x1BD11BDAu;
  x0 += k0; x1 += k1;
#define TFR(r) { x0 += x1; x1 = (x1 << (r)) | (x1 >> (32 - (r))); x1 ^= x0; }
  TFR(13) TFR(15) TFR(26) TFR(6)
  x0 += k1;  x1 += ks2 + 1u;
  TFR(17) TFR(29) TFR(16) TFR(24)
  x0 += ks2; x1 += k0 + 2u;
  TFR(13) TFR(15) TFR(26) TFR(6)
  x0 += k0;  x1 += k1 + 3u;
  TFR(17) TFR(29) TFR(16) TFR(24)
  x0 += k1;  x1 += ks2 + 4u;
  TFR(13) TFR(15) TFR(26) TFR(6)
  x0 += ks2; x1 += k0 + 5u;
#undef TFR
  KP o; o.a = x0; o.b = x1; return o;
}

// bits -> N(0,1) matching jax.random.normal f32 (erfinv = XLA/Giles poly).
__device__ __forceinline__ float n01(u32 bits) {
  float f = __uint_as_float((bits >> 9) | 0x3f800000u) - 1.0f;
  float u = fmaxf(-0.99999994f, f * 2.0f - 0.99999994f);
  float w = -log1pf(-u * u);
  float p;
  if (w < 5.0f) {
    float z = w - 2.5f;
    p = 2.81022636e-08f;
    p = 3.43273939e-07f  + p * z;
    p = -3.5233877e-06f  + p * z;
    p = -4.39150654e-06f + p * z;
    p = 0.00021858087f   + p * z;
    p = -0.00125372503f  + p * z;
    p = -0.00417768164f  + p * z;
    p = 0.246640727f     + p * z;
    p = 1.50140941f      + p * z;
  } else {
    float z = sqrtf(w) - 3.0f;
    p = -0.000200214257f;
    p = 0.000100950558f  + p * z;
    p = 0.00134934322f   + p * z;
    p = -0.00367342844f  + p * z;
    p = 0.00573950773f   + p * z;
    p = -0.0076224613f   + p * z;
    p = 0.00943887047f   + p * z;
    p = 1.00167406f      + p * z;
    p = 2.83297682f      + p * z;
  }
  return 1.41421356237f * (p * u);
}

// LDS pool carve (bytes): [wbuf 8x516 f32 =16512][inb 2x64x68 f32 =34816]
// gpart 16x520 f32 = 33280 ALIASES [0,33280) (wbuf+inb dead by then; stage
// boundaries are barrier-separated). bias2 (8 f32) at 51328.
#define POOL_BYTES 51360
#define WBUF_OFF   0
#define INB_OFF    16512
#define BIAS_OFF   51328

template<int LAYER>
__device__ void step_body(
    const float* __restrict__ x,
    const float* __restrict__ wihmu, const float* __restrict__ whhmu,
    const float* __restrict__ bihmu, const float* __restrict__ bhhmu,
    float* __restrict__ ws, float* __restrict__ out, int t, char* pool)
{
  constexpr int Kin  = LAYER ? Hn : INn;
  constexpr int Ktot = Kin + Hn;      // 512 or 320
  constexpr int nch  = Ktot / 64;     // 8 or 5
  const int tid = threadIdx.x;
  const int lb  = blockIdx.x & 127;
  const int j0  = lb * 2;
  const int ts  = LAYER ? (t - 1) : t;
  const int tsb = ts & 1;

  float* wbuf  = (float*)(pool + WBUF_OFF);   // [8][516]
  float* inb   = (float*)(pool + INB_OFF);    // [2][64][68]
  float* gpart = (float*)(pool + 0);          // [16][520], aliases wbuf+inb
  float* bias2 = (float*)(pool + BIAS_OFF);   // [8]

  const u32* kp = (const u32*)(ws + OFF_KEYS) + (LAYER * Tn + ts) * 8;

  const float* elv_ih  = ws + (LAYER ? OFF_ELV_WIH1 : OFF_ELV_WIH0);
  const float* elv_hh  = ws + (LAYER ? OFF_ELV_WHH1 : OFF_ELV_WHH0);
  const float* belv_ih = ws + OFF_ELV_B + LAYER * 2048;
  const float* belv_hh = belv_ih + 1024;
  const float* hprev   = ws + (LAYER ? OFF_H1 : OFF_H0) + tsb * BH;
  const float* ring    = ws + OFF_RING + tsb * BH;

  // ---- input chunk loaders (global -> regs -> swizzled LDS) -------------
  auto src_addr = [&](int c, int b, int q4) -> const float* {
    if (LAYER == 0) {
      if (c == 0) return x + (b * Tn + ts) * INn + q4;
      return hprev + b * Hn + (c - 1) * 64 + q4;
    } else {
      if (c < 4) return ring + b * Hn + c * 64 + q4;
      return hprev + b * Hn + (c - 4) * 64 + q4;
    }
  };
  float4 pf[4];
  auto stage_load = [&](int c) {
    #pragma unroll
    for (int m = 0; m < 4; ++m) {
      int f = tid + 256 * m, b = f >> 4, q4 = (f & 15) * 4;
      pf[m] = *(const float4*)src_addr(c, b, q4);
    }
  };
  auto stage_write = [&](int buf) {
    #pragma unroll
    for (int m = 0; m < 4; ++m) {
      int f = tid + 256 * m, b = f >> 4, seg = f & 15;
      int col = 4 * (seg ^ ((b >> 3) & 7));
      *(float4*)&inb[((buf << 6) + b) * 68 + col] = pf[m];
    }
  };

  // ---- phase 1: issue chunk-0 loads, then sample weights into LDS -------
  stage_load(0);

  const u32 kwa = kp[0], kwb = kp[1], kua = kp[2], kub = kp[3];
  #pragma unroll
  for (int it = 0; it < (Ktot + 255) / 256; ++it) {
    int k = tid + it * 256;
    if (k < Ktot) {
      bool iswih = k < Kin;
      u32 ka = iswih ? kwa : kua, kb = iswih ? kwb : kub;
      const float* mup  = iswih ? wihmu  : whhmu;
      const float* elvp = iswih ? elv_ih : elv_hh;
      int kk = iswih ? k : k - Kin;
      int kstride = iswih ? Kin : Hn;
      #pragma unroll
      for (int gi = 0; gi < 8; ++gi) {           // gi = jj*4 + s
        int g = (gi & 3) * Hn + j0 + (gi >> 2);
        int i = g * kstride + kk;
        KP r = tf(ka, kb, 0u, (u32)i);
        wbuf[gi * 516 + k] = mup[i] + elvp[i] * n01(r.a ^ r.b);
      }
    }
  }
  if (tid < 8) {
    int g = (tid & 3) * Hn + j0 + (tid >> 2);
    KP rb = tf(kp[4], kp[5], 0u, (u32)g);
    KP rh = tf(kp[6], kp[7], 0u, (u32)g);
    bias2[tid] = bihmu[g] + belv_ih[g] * n01(rb.a ^ rb.b)
               + bhhmu[g] + belv_hh[g] * n01(rh.a ^ rh.b);
  }
  stage_write(0);
  __syncthreads();

  // ---- phase 2: chunked FMA, k-split 16, per-thread 8b x 4s tile --------
  const int kq = tid >> 4;          // 0..15 : k-quad within chunk
  const int bp = (tid >> 1) & 7;    // 0..7  : batch group (8 rows)
  const int jj = tid & 1;           // 0..1  : which j column
  const int colq = 4 * (kq ^ bp);   // swizzled inb column (holds quad kq)

  float acc[8][4];
  #pragma unroll
  for (int r = 0; r < 8; ++r)
    acc[r][0] = acc[r][1] = acc[r][2] = acc[r][3] = 0.f;

  #pragma unroll
  for (int c = 0; c < nch; ++c) {
    if (c + 1 < nch) stage_load(c + 1);
    float4 w4[4];
    #pragma unroll
    for (int s = 0; s < 4; ++s)
      w4[s] = *(const float4*)&wbuf[(jj * 4 + s) * 516 + c * 64 + kq * 4];
    #pragma unroll
    for (int r = 0; r < 8; ++r) {
      float4 in4 = *(const float4*)&inb[(((c & 1) << 6) + bp * 8 + r) * 68 + colq];
      #pragma unroll
      for (int s = 0; s < 4; ++s)
        acc[r][s] += in4.x * w4[s].x + in4.y * w4[s].y
                   + in4.z * w4[s].z + in4.w * w4[s].w;
    }
    if (c + 1 < nch) stage_write((c + 1) & 1);
    __syncthreads();
  }

  // ---- phase 3: k-partials to LDS (bp-swizzled), reduce, activate -------
  #pragma unroll
  for (int r = 0; r < 8; ++r) {
    float4 v = {acc[r][0], acc[r][1], acc[r][2], acc[r][3]};
    int col4 = (bp * 16 + r * 2 + jj) ^ bp;
    *(float4*)&gpart[kq * 520 + col4 * 4] = v;
  }
  __syncthreads();

  if (tid < 128) {
    const int b = tid >> 1, j2 = tid & 1;
    const int rbp = b >> 3, rr = b & 7;
    const int col4 = (rbp * 16 + rr * 2 + j2) ^ rbp;
    float4 gq = {0.f, 0.f, 0.f, 0.f};
    #pragma unroll
    for (int q = 0; q < 16; ++q) {
      float4 p = *(const float4*)&gpart[q * 520 + col4 * 4];
      gq.x += p.x; gq.y += p.y; gq.z += p.z; gq.w += p.w;
    }
    const int j = j0 + j2;
    float gI = gq.x + bias2[j2 * 4 + 0];
    float gF = gq.y + bias2[j2 * 4 + 1];
    float gG = gq.z + bias2[j2 * 4 + 2];
    float gO = gq.w + bias2[j2 * 4 + 3];

    float* cst = ws + (LAYER ? OFF_C1 : OFF_C0);
    float cp = cst[b * Hn + j];
    float si = 1.f / (1.f + expf(-gI));
    float sf = 1.f / (1.f + expf(-gF));
    float so = 1.f / (1.f + expf(-gO));
    float cn = sf * cp + si * tanhf(gG);
    float hn = so * tanhf(cn);
    cst[b * Hn + j] = cn;
    float* hnx = ws + (LAYER ? OFF_H1 : OFF_H0) + ((ts + 1) & 1) * BH;
    hnx[b * Hn + j] = hn;
    if (LAYER == 0) {
      ws[OFF_RING + tsb * BH + b * Hn + j] = hn;
      if (ts == Tn - 1) {
        out[OUT_HN + b * Hn + j] = hn;                 // h_n[0]
        out[OUT_HN + 2 * BH + b * Hn + j] = cn;        // c_n[0]
      }
    } else {
      out[b * (Tn * Hn) + ts * Hn + j] = hn;           // output[b][ts][j]
      if (ts == Tn - 1) {
        out[OUT_HN + BH + b * Hn + j] = hn;            // h_n[1]
        out[OUT_HN + 3 * BH + b * Hn + j] = cn;        // c_n[1]
      }
    }
  }
}

__global__ __launch_bounds__(256) void bayes_lstm_persist(
    const float* __restrict__ x,
    const float* __restrict__ wihmu0, const float* __restrict__ whhmu0,
    const float* __restrict__ bihmu0, const float* __restrict__ bhhmu0,
    const float* __restrict__ wihmu1, const float* __restrict__ whhmu1,
    const float* __restrict__ bihmu1, const float* __restrict__ bhhmu1,
    float* __restrict__ ws, float* __restrict__ out)
{
  __shared__ __align__(16) char pool[POOL_BYTES];
  int* cnt = (int*)(ws + OFF_BAR);
  const int layer = blockIdx.x >> 7;

  for (int t = 0; t <= Tn; ++t) {
    if (layer == 0) {
      if (t < Tn)
        step_body<0>(x, wihmu0, whhmu0, bihmu0, bhhmu0, ws, out, t, pool);
    } else {
      if (t >= 1)
        step_body<1>(x, wihmu1, whhmu1, bihmu1, bhhmu1, ws, out, t, pool);
    }
    if (t == Tn) break;              // no barrier needed after last stage
    // ---- device-scope grid barrier (monotonic counter, no reset) ----
    __syncthreads();
    if (threadIdx.x == 0) {
      __threadfence();               // release h/c/ring writes device-wide
      __hip_atomic_fetch_add(cnt, 1, __ATOMIC_RELEASE, __HIP_MEMORY_SCOPE_AGENT);
      const int target = 256 * (t + 1);
      while (__hip_atomic_load(cnt, __ATOMIC_ACQUIRE, __HIP_MEMORY_SCOPE_AGENT) < target)
        __builtin_amdgcn_s_sleep(2);
    }
    __syncthreads();
  }
}

__global__ __launch_bounds__(256) void bayes_lstm_prologue(
    const float* __restrict__ wihlv0, const float* __restrict__ whhlv0,
    const float* __restrict__ bihlv0, const float* __restrict__ bhhlv0,
    const float* __restrict__ wihlv1, const float* __restrict__ whhlv1,
    const float* __restrict__ bihlv1, const float* __restrict__ bhhlv1,
    float* __restrict__ ws)
{
  const int gt = blockIdx.x * 256 + threadIdx.x;
  const int stride = gridDim.x * 256;
  for (int i = gt; i < 65536; i += stride)
    ws[OFF_ELV_WIH0 + i] = expf(0.5f * wihlv0[i]);
  for (int i = gt; i < 262144; i += stride) {
    ws[OFF_ELV_WHH0 + i] = expf(0.5f * whhlv0[i]);
    ws[OFF_ELV_WIH1 + i] = expf(0.5f * wihlv1[i]);
    ws[OFF_ELV_WHH1 + i] = expf(0.5f * whhlv1[i]);
  }
  for (int i = gt; i < 1024; i += stride) {
    ws[OFF_ELV_B + i]        = expf(0.5f * bihlv0[i]);
    ws[OFF_ELV_B + 1024 + i] = expf(0.5f * bhhlv0[i]);
    ws[OFF_ELV_B + 2048 + i] = expf(0.5f * bihlv1[i]);
    ws[OFF_ELV_B + 3072 + i] = expf(0.5f * bhhlv1[i]);
  }
  for (int i = gt; i < STATE_FLOATS; i += stride)
    ws[OFF_RING + i] = 0.f;
  if (gt == 0)
    *(int*)(ws + OFF_BAR) = 0;       // reset grid-barrier counter every call
  // threefry key table: (layer, ts) -> {kw, ku, kbi, kbh}
  if (gt < 2 * Tn) {
    int l = gt >> 7, ts = gt & 127;
    KP lk  = tf(0u, 42u, 0u, (u32)l);       // fold_in(key(42), l)
    KP kt  = tf(lk.a, lk.b, 0u, (u32)ts);   // split(layer_key, T)[ts]
    KP kw  = tf(kt.a, kt.b, 0u, 0u);
    KP ku  = tf(kt.a, kt.b, 0u, 1u);
    KP kbi = tf(kt.a, kt.b, 0u, 2u);
    KP kbh = tf(kt.a, kt.b, 0u, 3u);
    u32* kp = (u32*)(ws + OFF_KEYS) + gt * 8;
    kp[0] = kw.a;  kp[1] = kw.b;  kp[2] = ku.a;  kp[3] = ku.b;
    kp[4] = kbi.a; kp[5] = kbi.b; kp[6] = kbh.a; kp[7] = kbh.b;
  }
}

extern "C" void kernel_launch(void* const* d_in, const int* in_sizes, int n_in,
                              void* d_out, int out_size, void* d_ws, size_t ws_size,
                              hipStream_t stream) {
  (void)in_sizes; (void)n_in; (void)out_size;
  if (ws_size < (size_t)WS_FLOATS * sizeof(float)) return;  // need 3.96 MiB

  const float* x      = (const float*)d_in[0];
  const float* wihmu0 = (const float*)d_in[1];
  const float* wihlv0 = (const float*)d_in[2];
  const float* whhmu0 = (const float*)d_in[3];
  const float* whhlv0 = (const float*)d_in[4];
  const float* bihmu0 = (const float*)d_in[5];
  const float* bihlv0 = (const float*)d_in[6];
  const float* bhhmu0 = (const float*)d_in[7];
  const float* bhhlv0 = (const float*)d_in[8];
  const float* wihmu1 = (const float*)d_in[9];
  const float* wihlv1 = (const float*)d_in[10];
  const float* whhmu1 = (const float*)d_in[11];
  const float* whhlv1 = (const float*)d_in[12];
  const float* bihmu1 = (const float*)d_in[13];
  const float* bihlv1 = (const float*)d_in[14];
  const float* bhhmu1 = (const float*)d_in[15];
  const float* bhhlv1 = (const float*)d_in[16];
  float* ws  = (float*)d_ws;
  float* out = (float*)d_out;

  bayes_lstm_prologue<<<dim3(256), dim3(256), 0, stream>>>(
      wihlv0, whhlv0, bihlv0, bhhlv0, wihlv1, whhlv1, bihlv1, bhhlv1, ws);

  bayes_lstm_persist<<<dim3(256), dim3(256), 0, stream>>>(
      x, wihmu0, whhmu0, bihmu0, bhhmu0,
      wihmu1, whhmu1, bihmu1, bhhmu1, ws, out);
}

// Round 5
// 4866.885 us; speedup vs baseline: 1.2839x; 1.2839x over previous
//
#include <hip/hip_runtime.h>
#include <stdint.h>

// BayesLSTM R4: persistent kernel, flag-based grid barrier (parallel arrival
// stores + master gather + go broadcast) replacing R3's serialized
// atomic-counter barrier (256 contended RMWs/stage ~= 40us/stage).
// Weight sampling for stage t+1 is executed AFTER posting arrival, i.e.
// hidden under the barrier wait (it depends only on static keys/mu/elv).
// LDS: wbuf stays live across the barrier; gpart now aliases inb.

typedef unsigned int u32;

#define Bn 64
#define Tn 128
#define INn 64
#define Hn 256
#define Gn 1024
#define BH (Bn * Hn)

#define OFF_ELV_WIH0 0
#define OFF_ELV_WHH0 65536
#define OFF_ELV_WIH1 327680
#define OFF_ELV_WHH1 589824
#define OFF_ELV_B    851968            // bih0,bhh0,bih1,bhh1 (4*1024)
#define OFF_RING     856064
#define OFF_H0       (OFF_RING + 2 * BH)
#define OFF_H1       (OFF_H0 + 2 * BH)
#define OFF_C0       (OFF_H1 + 2 * BH)
#define OFF_C1       (OFF_C0 + BH)
#define OFF_KEYS     (OFF_C1 + BH)           // 2*128*8 u32 key table
#define OFF_SLOTS    (OFF_KEYS + 2 * Tn * 8) // 256 slots x 32 u32 (128B apart)
#define OFF_GO       (OFF_SLOTS + 256 * 32)
#define WS_FLOATS    (OFF_GO + 32)           // 997408 floats = 3.99 MiB
#define STATE_FLOATS (OFF_KEYS - OFF_RING)
#define OUT_HN       (Bn * Tn * Hn)

struct KP { u32 a, b; };

// Threefry-2x32, 20 rounds — matches jax/_src/prng.py exactly.
__device__ __forceinline__ KP tf(u32 k0, u32 k1, u32 x0, u32 x1) {
  u32 ks2 = k0 ^ k1 ^ 0x1BD11BDAu;
  x0 += k0; x1 += k1;
#define TFR(r) { x0 += x1; x1 = (x1 << (r)) | (x1 >> (32 - (r))); x1 ^= x0; }
  TFR(13) TFR(15) TFR(26) TFR(6)
  x0 += k1;  x1 += ks2 + 1u;
  TFR(17) TFR(29) TFR(16) TFR(24)
  x0 += ks2; x1 += k0 + 2u;
  TFR(13) TFR(15) TFR(26) TFR(6)
  x0 += k0;  x1 += k1 + 3u;
  TFR(17) TFR(29) TFR(16) TFR(24)
  x0 += k1;  x1 += ks2 + 4u;
  TFR(13) TFR(15) TFR(26) TFR(6)
  x0 += ks2; x1 += k0 + 5u;
#undef TFR
  KP o; o.a = x0; o.b = x1; return o;
}

// bits -> N(0,1) matching jax.random.normal f32 (erfinv = XLA/Giles poly).
__device__ __forceinline__ float n01(u32 bits) {
  float f = __uint_as_float((bits >> 9) | 0x3f800000u) - 1.0f;
  float u = fmaxf(-0.99999994f, f * 2.0f - 0.99999994f);
  float w = -log1pf(-u * u);
  float p;
  if (w < 5.0f) {
    float z = w - 2.5f;
    p = 2.81022636e-08f;
    p = 3.43273939e-07f  + p * z;
    p = -3.5233877e-06f  + p * z;
    p = -4.39150654e-06f + p * z;
    p = 0.00021858087f   + p * z;
    p = -0.00125372503f  + p * z;
    p = -0.00417768164f  + p * z;
    p = 0.246640727f     + p * z;
    p = 1.50140941f      + p * z;
  } else {
    float z = sqrtf(w) - 3.0f;
    p = -0.000200214257f;
    p = 0.000100950558f  + p * z;
    p = 0.00134934322f   + p * z;
    p = -0.00367342844f  + p * z;
    p = 0.00573950773f   + p * z;
    p = -0.0076224613f   + p * z;
    p = 0.00943887047f   + p * z;
    p = 1.00167406f      + p * z;
    p = 2.83297682f      + p * z;
  }
  return 1.41421356237f * (p * u);
}

// LDS pool carve (bytes): [wbuf 8x516 f32 =16512 | PERSISTS across barrier]
// [inb 2x64x68 f32 =34816 at 16512] ; gpart 16x520 f32 =33280 ALIASES inb
// (inb dead after phase-2 loop). bias2 (8 f32) at 51328.
#define POOL_BYTES 51360
#define WBUF_OFF   0
#define INB_OFF    16512
#define BIAS_OFF   51328

// Sample weights + bias for (LAYER, ts) into wbuf/bias2. Depends only on
// key table + mu + elv (static) — safe to run during barrier wait.
template<int LAYER>
__device__ __forceinline__ void sample_weights(
    const float* __restrict__ wihmu, const float* __restrict__ whhmu,
    const float* __restrict__ bihmu, const float* __restrict__ bhhmu,
    const float* __restrict__ ws, float* __restrict__ wbuf,
    float* __restrict__ bias2, int ts, int j0, int tid)
{
  constexpr int Kin  = LAYER ? Hn : INn;
  constexpr int Ktot = Kin + Hn;
  if (ts >= Tn) return;
  const u32* kp = (const u32*)(ws + OFF_KEYS) + (LAYER * Tn + ts) * 8;
  const float* elv_ih  = ws + (LAYER ? OFF_ELV_WIH1 : OFF_ELV_WIH0);
  const float* elv_hh  = ws + (LAYER ? OFF_ELV_WHH1 : OFF_ELV_WHH0);
  const float* belv_ih = ws + OFF_ELV_B + LAYER * 2048;
  const float* belv_hh = belv_ih + 1024;

  const u32 kwa = kp[0], kwb = kp[1], kua = kp[2], kub = kp[3];
  #pragma unroll
  for (int it = 0; it < (Ktot + 255) / 256; ++it) {
    int k = tid + it * 256;
    if (k < Ktot) {
      bool iswih = k < Kin;
      u32 ka = iswih ? kwa : kua, kb = iswih ? kwb : kub;
      const float* mup  = iswih ? wihmu  : whhmu;
      const float* elvp = iswih ? elv_ih : elv_hh;
      int kk = iswih ? k : k - Kin;
      int kstride = iswih ? Kin : Hn;
      #pragma unroll
      for (int gi = 0; gi < 8; ++gi) {           // gi = jj*4 + s
        int g = (gi & 3) * Hn + j0 + (gi >> 2);
        int i = g * kstride + kk;
        KP r = tf(ka, kb, 0u, (u32)i);
        wbuf[gi * 516 + k] = mup[i] + elvp[i] * n01(r.a ^ r.b);
      }
    }
  }
  if (tid < 8) {
    int g = (tid & 3) * Hn + j0 + (tid >> 2);
    KP rb = tf(kp[4], kp[5], 0u, (u32)g);
    KP rh = tf(kp[6], kp[7], 0u, (u32)g);
    bias2[tid] = bihmu[g] + belv_ih[g] * n01(rb.a ^ rb.b)
               + bhhmu[g] + belv_hh[g] * n01(rh.a ^ rh.b);
  }
}

// Step body: consumes pre-sampled wbuf/bias2; stages inputs, chunked FMA
// (k-split 16), reduces + activates, writes h/c/ring/out.
template<int LAYER>
__device__ void step_body(
    const float* __restrict__ x,
    float* __restrict__ ws, float* __restrict__ out, int t, char* pool)
{
  constexpr int Kin  = LAYER ? Hn : INn;
  constexpr int Ktot = Kin + Hn;      // 512 or 320
  constexpr int nch  = Ktot / 64;     // 8 or 5
  const int tid = threadIdx.x;
  const int lb  = blockIdx.x & 127;
  const int j0  = lb * 2;
  const int ts  = LAYER ? (t - 1) : t;
  const int tsb = ts & 1;

  float* wbuf  = (float*)(pool + WBUF_OFF);   // [8][516] (pre-filled)
  float* inb   = (float*)(pool + INB_OFF);    // [2][64][68]
  float* gpart = (float*)(pool + INB_OFF);    // [16][520], aliases inb
  float* bias2 = (float*)(pool + BIAS_OFF);   // [8]   (pre-filled)

  const float* hprev = ws + (LAYER ? OFF_H1 : OFF_H0) + tsb * BH;
  const float* ring  = ws + OFF_RING + tsb * BH;

  auto src_addr = [&](int c, int b, int q4) -> const float* {
    if (LAYER == 0) {
      if (c == 0) return x + (b * Tn + ts) * INn + q4;
      return hprev + b * Hn + (c - 1) * 64 + q4;
    } else {
      if (c < 4) return ring + b * Hn + c * 64 + q4;
      return hprev + b * Hn + (c - 4) * 64 + q4;
    }
  };
  float4 pf[4];
  auto stage_load = [&](int c) {
    #pragma unroll
    for (int m = 0; m < 4; ++m) {
      int f = tid + 256 * m, b = f >> 4, q4 = (f & 15) * 4;
      pf[m] = *(const float4*)src_addr(c, b, q4);
    }
  };
  auto stage_write = [&](int buf) {
    #pragma unroll
    for (int m = 0; m < 4; ++m) {
      int f = tid + 256 * m, b = f >> 4, seg = f & 15;
      int col = 4 * (seg ^ ((b >> 3) & 7));
      *(float4*)&inb[((buf << 6) + b) * 68 + col] = pf[m];
    }
  };

  // ---- phase 1: stage chunk 0 -------------------------------------------
  stage_load(0);
  stage_write(0);
  __syncthreads();

  // ---- phase 2: chunked FMA, k-split 16, per-thread 8b x 4s tile --------
  const int kq = tid >> 4;          // 0..15 : k-quad within chunk
  const int bp = (tid >> 1) & 7;    // 0..7  : batch group (8 rows)
  const int jj = tid & 1;           // 0..1  : which j column
  const int colq = 4 * (kq ^ bp);   // swizzled inb column (holds quad kq)

  float acc[8][4];
  #pragma unroll
  for (int r = 0; r < 8; ++r)
    acc[r][0] = acc[r][1] = acc[r][2] = acc[r][3] = 0.f;

  #pragma unroll
  for (int c = 0; c < nch; ++c) {
    if (c + 1 < nch) stage_load(c + 1);
    float4 w4[4];
    #pragma unroll
    for (int s = 0; s < 4; ++s)
      w4[s] = *(const float4*)&wbuf[(jj * 4 + s) * 516 + c * 64 + kq * 4];
    #pragma unroll
    for (int r = 0; r < 8; ++r) {
      float4 in4 = *(const float4*)&inb[(((c & 1) << 6) + bp * 8 + r) * 68 + colq];
      #pragma unroll
      for (int s = 0; s < 4; ++s)
        acc[r][s] += in4.x * w4[s].x + in4.y * w4[s].y
                   + in4.z * w4[s].z + in4.w * w4[s].w;
    }
    if (c + 1 < nch) stage_write((c + 1) & 1);
    __syncthreads();
  }

  // ---- phase 3: k-partials to LDS (bp-swizzled), reduce, activate -------
  #pragma unroll
  for (int r = 0; r < 8; ++r) {
    float4 v = {acc[r][0], acc[r][1], acc[r][2], acc[r][3]};
    int col4 = (bp * 16 + r * 2 + jj) ^ bp;
    *(float4*)&gpart[kq * 520 + col4 * 4] = v;
  }
  __syncthreads();

  if (tid < 128) {
    const int b = tid >> 1, j2 = tid & 1;
    const int rbp = b >> 3, rr = b & 7;
    const int col4 = (rbp * 16 + rr * 2 + j2) ^ rbp;
    float4 gq = {0.f, 0.f, 0.f, 0.f};
    #pragma unroll
    for (int q = 0; q < 16; ++q) {
      float4 p = *(const float4*)&gpart[q * 520 + col4 * 4];
      gq.x += p.x; gq.y += p.y; gq.z += p.z; gq.w += p.w;
    }
    const int j = j0 + j2;
    float gI = gq.x + bias2[j2 * 4 + 0];
    float gF = gq.y + bias2[j2 * 4 + 1];
    float gG = gq.z + bias2[j2 * 4 + 2];
    float gO = gq.w + bias2[j2 * 4 + 3];

    float* cst = ws + (LAYER ? OFF_C1 : OFF_C0);
    float cp = cst[b * Hn + j];
    float si = 1.f / (1.f + expf(-gI));
    float sf = 1.f / (1.f + expf(-gF));
    float so = 1.f / (1.f + expf(-gO));
    float cn = sf * cp + si * tanhf(gG);
    float hn = so * tanhf(cn);
    cst[b * Hn + j] = cn;
    float* hnx = ws + (LAYER ? OFF_H1 : OFF_H0) + ((ts + 1) & 1) * BH;
    hnx[b * Hn + j] = hn;
    if (LAYER == 0) {
      ws[OFF_RING + tsb * BH + b * Hn + j] = hn;
      if (ts == Tn - 1) {
        out[OUT_HN + b * Hn + j] = hn;                 // h_n[0]
        out[OUT_HN + 2 * BH + b * Hn + j] = cn;        // c_n[0]
      }
    } else {
      out[b * (Tn * Hn) + ts * Hn + j] = hn;           // output[b][ts][j]
      if (ts == Tn - 1) {
        out[OUT_HN + BH + b * Hn + j] = hn;            // h_n[1]
        out[OUT_HN + 3 * BH + b * Hn + j] = cn;        // c_n[1]
      }
    }
  }
}

__global__ __launch_bounds__(256) void bayes_lstm_persist(
    const float* __restrict__ x,
    const float* __restrict__ wihmu0, const float* __restrict__ whhmu0,
    const float* __restrict__ bihmu0, const float* __restrict__ bhhmu0,
    const float* __restrict__ wihmu1, const float* __restrict__ whhmu1,
    const float* __restrict__ bihmu1, const float* __restrict__ bhhmu1,
    float* __restrict__ ws, float* __restrict__ out)
{
  __shared__ __align__(16) char pool[POOL_BYTES];
  const int tid = threadIdx.x, bid = blockIdx.x;
  const int layer = bid >> 7, j0 = (bid & 127) * 2;
  float* wbuf  = (float*)(pool + WBUF_OFF);
  float* bias2 = (float*)(pool + BIAS_OFF);
  u32* slots = (u32*)(ws + OFF_SLOTS);
  u32* go    = (u32*)(ws + OFF_GO);

  // prefetch stage-0 weights (only L0 works at stage 0)
  if (layer == 0)
    sample_weights<0>(wihmu0, whhmu0, bihmu0, bhhmu0, ws, wbuf, bias2, 0, j0, tid);
  __syncthreads();

  for (int t = 0; t <= Tn; ++t) {
    if (layer == 0) {
      if (t < Tn) step_body<0>(x, ws, out, t, pool);
    } else {
      if (t >= 1) step_body<1>(x, ws, out, t, pool);
    }
    if (t == Tn) break;

    // ---- flag barrier: arrive, sample next weights (hidden), wait -------
    __syncthreads();                 // all h/c/ring/out writes drained (vmcnt)
    if (tid == 0) {
      __threadfence();               // agent-scope release of block's writes
      __hip_atomic_store(slots + bid * 32, (u32)(t + 1),
                         __ATOMIC_RELEASE, __HIP_MEMORY_SCOPE_AGENT);
    }
    // sample stage-(t+1) weights while the barrier resolves
    if (layer == 0)
      sample_weights<0>(wihmu0, whhmu0, bihmu0, bhhmu0, ws, wbuf, bias2, t + 1, j0, tid);
    else
      sample_weights<1>(wihmu1, whhmu1, bihmu1, bhhmu1, ws, wbuf, bias2, t, j0, tid);

    if (bid == 0) {                  // master: gather 256 slots in parallel
      u32* myslot = slots + tid * 32;
      while (__hip_atomic_load(myslot, __ATOMIC_ACQUIRE,
                               __HIP_MEMORY_SCOPE_AGENT) < (u32)(t + 1))
        __builtin_amdgcn_s_sleep(1);
      __syncthreads();
      if (tid == 0)
        __hip_atomic_store(go, (u32)(t + 1),
                           __ATOMIC_RELEASE, __HIP_MEMORY_SCOPE_AGENT);
    }
    if (tid == 0) {                  // everyone: wait for go broadcast
      while (__hip_atomic_load(go, __ATOMIC_ACQUIRE,
                               __HIP_MEMORY_SCOPE_AGENT) < (u32)(t + 1))
        __builtin_amdgcn_s_sleep(1);
    }
    __syncthreads();
  }
}

__global__ __launch_bounds__(256) void bayes_lstm_prologue(
    const float* __restrict__ wihlv0, const float* __restrict__ whhlv0,
    const float* __restrict__ bihlv0, const float* __restrict__ bhhlv0,
    const float* __restrict__ wihlv1, const float* __restrict__ whhlv1,
    const float* __restrict__ bihlv1, const float* __restrict__ bhhlv1,
    float* __restrict__ ws)
{
  const int gt = blockIdx.x * 256 + threadIdx.x;
  const int stride = gridDim.x * 256;
  for (int i = gt; i < 65536; i += stride)
    ws[OFF_ELV_WIH0 + i] = expf(0.5f * wihlv0[i]);
  for (int i = gt; i < 262144; i += stride) {
    ws[OFF_ELV_WHH0 + i] = expf(0.5f * whhlv0[i]);
    ws[OFF_ELV_WIH1 + i] = expf(0.5f * wihlv1[i]);
    ws[OFF_ELV_WHH1 + i] = expf(0.5f * whhlv1[i]);
  }
  for (int i = gt; i < 1024; i += stride) {
    ws[OFF_ELV_B + i]        = expf(0.5f * bihlv0[i]);
    ws[OFF_ELV_B + 1024 + i] = expf(0.5f * bhhlv0[i]);
    ws[OFF_ELV_B + 2048 + i] = expf(0.5f * bihlv1[i]);
    ws[OFF_ELV_B + 3072 + i] = expf(0.5f * bhhlv1[i]);
  }
  for (int i = gt; i < STATE_FLOATS; i += stride)
    ws[OFF_RING + i] = 0.f;
  for (int i = gt; i < 256 * 32 + 32; i += stride)
    ws[OFF_SLOTS + i] = 0.f;         // reset barrier slots + go every call
  // threefry key table: (layer, ts) -> {kw, ku, kbi, kbh}
  if (gt < 2 * Tn) {
    int l = gt >> 7, ts = gt & 127;
    KP lk  = tf(0u, 42u, 0u, (u32)l);       // fold_in(key(42), l)
    KP kt  = tf(lk.a, lk.b, 0u, (u32)ts);   // split(layer_key, T)[ts]
    KP kw  = tf(kt.a, kt.b, 0u, 0u);
    KP ku  = tf(kt.a, kt.b, 0u, 1u);
    KP kbi = tf(kt.a, kt.b, 0u, 2u);
    KP kbh = tf(kt.a, kt.b, 0u, 3u);
    u32* kp = (u32*)(ws + OFF_KEYS) + gt * 8;
    kp[0] = kw.a;  kp[1] = kw.b;  kp[2] = ku.a;  kp[3] = ku.b;
    kp[4] = kbi.a; kp[5] = kbi.b; kp[6] = kbh.a; kp[7] = kbh.b;
  }
}

extern "C" void kernel_launch(void* const* d_in, const int* in_sizes, int n_in,
                              void* d_out, int out_size, void* d_ws, size_t ws_size,
                              hipStream_t stream) {
  (void)in_sizes; (void)n_in; (void)out_size;
  if (ws_size < (size_t)WS_FLOATS * sizeof(float)) return;  // need 3.99 MiB

  const float* x      = (const float*)d_in[0];
  const float* wihmu0 = (const float*)d_in[1];
  const float* wihlv0 = (const float*)d_in[2];
  const float* whhmu0 = (const float*)d_in[3];
  const float* whhlv0 = (const float*)d_in[4];
  const float* bihmu0 = (const float*)d_in[5];
  const float* bihlv0 = (const float*)d_in[6];
  const float* bhhmu0 = (const float*)d_in[7];
  const float* bhhlv0 = (const float*)d_in[8];
  const float* wihmu1 = (const float*)d_in[9];
  const float* wihlv1 = (const float*)d_in[10];
  const float* whhmu1 = (const float*)d_in[11];
  const float* whhlv1 = (const float*)d_in[12];
  const float* bihmu1 = (const float*)d_in[13];
  const float* bihlv1 = (const float*)d_in[14];
  const float* bhhmu1 = (const float*)d_in[15];
  const float* bhhlv1 = (const float*)d_in[16];
  float* ws  = (float*)d_ws;
  float* out = (float*)d_out;

  bayes_lstm_prologue<<<dim3(256), dim3(256), 0, stream>>>(
      wihlv0, whhlv0, bihlv0, bhhlv0, wihlv1, whhlv1, bihlv1, bhhlv1, ws);

  bayes_lstm_persist<<<dim3(256), dim3(256), 0, stream>>>(
      x, wihmu0, whhmu0, bihmu0, bhhmu0,
      wihmu1, whhmu1, bihmu1, bhhmu1, ws, out);
}

// Round 7
// 2512.586 us; speedup vs baseline: 2.4870x; 1.9370x over previous
//
#include <hip/hip_runtime.h>
#include <stdint.h>

// BayesLSTM R6: R5 (persistent kernel, relaxed sc1 data+flag protocol) plus
// the ordering fix: compiler memory barriers after every flag-spin exit so
// post-barrier h/ring loads cannot be hoisted above the flag observation
// (R5's intermittent replay divergence). Staging loads widened to 64-bit
// atomic (float2) — half the coherent-load instructions, same verified LDS
// swizzle layout. Cell state in registers; weight sampling for stage t+1
// hidden under the barrier wait.

typedef unsigned int u32;
typedef unsigned long long u64;

#define Bn 64
#define Tn 128
#define INn 64
#define Hn 256
#define Gn 1024
#define BH (Bn * Hn)

#define OFF_ELV_WIH0 0
#define OFF_ELV_WHH0 65536
#define OFF_ELV_WIH1 327680
#define OFF_ELV_WHH1 589824
#define OFF_ELV_B    851968            // bih0,bhh0,bih1,bhh1 (4*1024)
#define OFF_RING     856064
#define OFF_H0       (OFF_RING + 2 * BH)
#define OFF_H1       (OFF_H0 + 2 * BH)
#define OFF_KEYS     (OFF_H1 + 2 * BH)       // 2*128*8 u32 key table
#define OFF_SLOTS    (OFF_KEYS + 2 * Tn * 8) // 256 slots x 32 u32 (128B apart)
#define OFF_GO       (OFF_SLOTS + 256 * 32)
#define WS_FLOATS    (OFF_GO + 32)           // ~3.87 MiB
#define STATE_FLOATS (OFF_KEYS - OFF_RING)
#define OUT_HN       (Bn * Tn * Hn)

struct KP { u32 a, b; };

// ---- coherent (agent-scope, relaxed) access helpers ----------------------
__device__ __forceinline__ float2 ld_coh2(const float* p) {
  u64 v = __hip_atomic_load((const u64*)p, __ATOMIC_RELAXED,
                            __HIP_MEMORY_SCOPE_AGENT);
  float2 f; f.x = __uint_as_float((u32)v); f.y = __uint_as_float((u32)(v >> 32));
  return f;
}
__device__ __forceinline__ void st_coh(float* p, float v) {
  __hip_atomic_store(p, v, __ATOMIC_RELAXED, __HIP_MEMORY_SCOPE_AGENT);
}
__device__ __forceinline__ u32 ld_flag(const u32* p) {
  return __hip_atomic_load(p, __ATOMIC_RELAXED, __HIP_MEMORY_SCOPE_AGENT);
}
__device__ __forceinline__ void st_flag(u32* p, u32 v) {
  __hip_atomic_store(p, v, __ATOMIC_RELAXED, __HIP_MEMORY_SCOPE_AGENT);
}

// Threefry-2x32, 20 rounds — matches jax/_src/prng.py exactly.
__device__ __forceinline__ KP tf(u32 k0, u32 k1, u32 x0, u32 x1) {
  u32 ks2 = k0 ^ k1 ^ 0x1BD11BDAu;
  x0 += k0; x1 += k1;
#define TFR(r) { x0 += x1; x1 = (x1 << (r)) | (x1 >> (32 - (r))); x1 ^= x0; }
  TFR(13) TFR(15) TFR(26) TFR(6)
  x0 += k1;  x1 += ks2 + 1u;
  TFR(17) TFR(29) TFR(16) TFR(24)
  x0 += ks2; x1 += k0 + 2u;
  TFR(13) TFR(15) TFR(26) TFR(6)
  x0 += k0;  x1 += k1 + 3u;
  TFR(17) TFR(29) TFR(16) TFR(24)
  x0 += k1;  x1 += ks2 + 4u;
  TFR(13) TFR(15) TFR(26) TFR(6)
  x0 += ks2; x1 += k0 + 5u;
#undef TFR
  KP o; o.a = x0; o.b = x1; return o;
}

// bits -> N(0,1) matching jax.random.normal f32 (erfinv = XLA/Giles poly).
__device__ __forceinline__ float n01(u32 bits) {
  float f = __uint_as_float((bits >> 9) | 0x3f800000u) - 1.0f;
  float u = fmaxf(-0.99999994f, f * 2.0f - 0.99999994f);
  float w = -log1pf(-u * u);
  float p;
  if (w < 5.0f) {
    float z = w - 2.5f;
    p = 2.81022636e-08f;
    p = 3.43273939e-07f  + p * z;
    p = -3.5233877e-06f  + p * z;
    p = -4.39150654e-06f + p * z;
    p = 0.00021858087f   + p * z;
    p = -0.00125372503f  + p * z;
    p = -0.00417768164f  + p * z;
    p = 0.246640727f     + p * z;
    p = 1.50140941f      + p * z;
  } else {
    float z = sqrtf(w) - 3.0f;
    p = -0.000200214257f;
    p = 0.000100950558f  + p * z;
    p = 0.00134934322f   + p * z;
    p = -0.00367342844f  + p * z;
    p = 0.00573950773f   + p * z;
    p = -0.0076224613f   + p * z;
    p = 0.00943887047f   + p * z;
    p = 1.00167406f      + p * z;
    p = 2.83297682f      + p * z;
  }
  return 1.41421356237f * (p * u);
}

// LDS pool carve (bytes): [wbuf 8x516 f32 =16512 | PERSISTS across barrier]
// [inb 2x64x68 f32 =34816 at 16512] ; gpart 16x520 f32 =33280 ALIASES inb.
// bias2 (8 f32) at 51328.
#define POOL_BYTES 51360
#define WBUF_OFF   0
#define INB_OFF    16512
#define BIAS_OFF   51328

// Sample weights + bias for (LAYER, ts) into wbuf/bias2. Depends only on
// key table + mu + elv (all L2-warm plain loads) — runs under barrier wait.
template<int LAYER>
__device__ __forceinline__ void sample_weights(
    const float* __restrict__ wihmu, const float* __restrict__ whhmu,
    const float* __restrict__ bihmu, const float* __restrict__ bhhmu,
    const float* __restrict__ ws, float* __restrict__ wbuf,
    float* __restrict__ bias2, int ts, int j0, int tid)
{
  constexpr int Kin  = LAYER ? Hn : INn;
  constexpr int Ktot = Kin + Hn;
  if (ts >= Tn) return;
  const u32* kp = (const u32*)(ws + OFF_KEYS) + (LAYER * Tn + ts) * 8;
  const float* elv_ih  = ws + (LAYER ? OFF_ELV_WIH1 : OFF_ELV_WIH0);
  const float* elv_hh  = ws + (LAYER ? OFF_ELV_WHH1 : OFF_ELV_WHH0);
  const float* belv_ih = ws + OFF_ELV_B + LAYER * 2048;
  const float* belv_hh = belv_ih + 1024;

  const u32 kwa = kp[0], kwb = kp[1], kua = kp[2], kub = kp[3];
  #pragma unroll
  for (int it = 0; it < (Ktot + 255) / 256; ++it) {
    int k = tid + it * 256;
    if (k < Ktot) {
      bool iswih = k < Kin;
      u32 ka = iswih ? kwa : kua, kb = iswih ? kwb : kub;
      const float* mup  = iswih ? wihmu  : whhmu;
      const float* elvp = iswih ? elv_ih : elv_hh;
      int kk = iswih ? k : k - Kin;
      int kstride = iswih ? Kin : Hn;
      #pragma unroll
      for (int gi = 0; gi < 8; ++gi) {           // gi = jj*4 + s
        int g = (gi & 3) * Hn + j0 + (gi >> 2);
        int i = g * kstride + kk;
        KP r = tf(ka, kb, 0u, (u32)i);
        wbuf[gi * 516 + k] = mup[i] + elvp[i] * n01(r.a ^ r.b);
      }
    }
  }
  if (tid < 8) {
    int g = (tid & 3) * Hn + j0 + (tid >> 2);
    KP rb = tf(kp[4], kp[5], 0u, (u32)g);
    KP rh = tf(kp[6], kp[7], 0u, (u32)g);
    bias2[tid] = bihmu[g] + belv_ih[g] * n01(rb.a ^ rb.b)
               + bhhmu[g] + belv_hh[g] * n01(rh.a ^ rh.b);
  }
}

// Step body: consumes pre-sampled wbuf/bias2; stages inputs (h/ring via
// 64-bit coherent loads, x plain), chunked FMA (k-split 16), reduce +
// activate; h/ring written via coherent scalar stores; c kept in `creg`.
template<int LAYER>
__device__ void step_body(
    const float* __restrict__ x,
    float* __restrict__ ws, float* __restrict__ out, int t, char* pool,
    float& creg)
{
  constexpr int Kin  = LAYER ? Hn : INn;
  constexpr int Ktot = Kin + Hn;      // 512 or 320
  constexpr int nch  = Ktot / 64;     // 8 or 5
  const int tid = threadIdx.x;
  const int lb  = blockIdx.x & 127;
  const int j0  = lb * 2;
  const int ts  = LAYER ? (t - 1) : t;
  const int tsb = ts & 1;

  float* wbuf  = (float*)(pool + WBUF_OFF);   // [8][516] (pre-filled)
  float* inb   = (float*)(pool + INB_OFF);    // [2][64][68]
  float* gpart = (float*)(pool + INB_OFF);    // [16][520], aliases inb
  float* bias2 = (float*)(pool + BIAS_OFF);   // [8]   (pre-filled)

  const float* hprev = ws + (LAYER ? OFF_H1 : OFF_H0) + tsb * BH;
  const float* ring  = ws + OFF_RING + tsb * BH;

  // ---- staging: lane pair-loads (8B): rows in (even,odd) pairs ----------
  const int lane = tid & 63, wv = tid >> 6;
  const int half = lane >> 5, sl = lane & 31;
  float2 pf[8];
  auto stage_load = [&](int c) {
    #pragma unroll
    for (int r = 0; r < 8; ++r) {
      int b = wv * 16 + r * 2 + half;
      int e = 2 * sl;                      // element within 64-float chunk
      if (LAYER == 0) {
        if (c == 0) { pf[r] = *(const float2*)&x[(b * Tn + ts) * INn + e]; }
        else        { pf[r] = ld_coh2(hprev + b * Hn + (c - 1) * 64 + e); }
      } else {
        if (c < 4)  { pf[r] = ld_coh2(ring + b * Hn + c * 64 + e); }
        else        { pf[r] = ld_coh2(hprev + b * Hn + (c - 4) * 64 + e); }
      }
    }
  };
  auto stage_write = [&](int buf) {
    const int q = sl >> 1, pos = (sl & 1) * 2;   // quad + within-quad offset
    #pragma unroll
    for (int r = 0; r < 8; ++r) {
      int b = wv * 16 + r * 2 + half;
      int col = 4 * (q ^ ((b >> 3) & 7)) + pos;
      *(float2*)&inb[((buf << 6) + b) * 68 + col] = pf[r];
    }
  };

  // ---- phase 1: stage chunk 0 -------------------------------------------
  stage_load(0);
  stage_write(0);
  __syncthreads();

  // ---- phase 2: chunked FMA, k-split 16, per-thread 8b x 4s tile --------
  const int kq = tid >> 4;          // 0..15 : k-quad within chunk
  const int bp = (tid >> 1) & 7;    // 0..7  : batch group (8 rows)
  const int jj = tid & 1;           // 0..1  : which j column
  const int colq = 4 * (kq ^ bp);   // swizzled inb column (holds quad kq)

  float acc[8][4];
  #pragma unroll
  for (int r = 0; r < 8; ++r)
    acc[r][0] = acc[r][1] = acc[r][2] = acc[r][3] = 0.f;

  #pragma unroll
  for (int c = 0; c < nch; ++c) {
    if (c + 1 < nch) stage_load(c + 1);
    float4 w4[4];
    #pragma unroll
    for (int s = 0; s < 4; ++s)
      w4[s] = *(const float4*)&wbuf[(jj * 4 + s) * 516 + c * 64 + kq * 4];
    #pragma unroll
    for (int r = 0; r < 8; ++r) {
      float4 in4 = *(const float4*)&inb[(((c & 1) << 6) + bp * 8 + r) * 68 + colq];
      #pragma unroll
      for (int s = 0; s < 4; ++s)
        acc[r][s] += in4.x * w4[s].x + in4.y * w4[s].y
                   + in4.z * w4[s].z + in4.w * w4[s].w;
    }
    if (c + 1 < nch) stage_write((c + 1) & 1);
    __syncthreads();
  }

  // ---- phase 3: k-partials to LDS (bp-swizzled), reduce, activate -------
  #pragma unroll
  for (int r = 0; r < 8; ++r) {
    float4 v = {acc[r][0], acc[r][1], acc[r][2], acc[r][3]};
    int col4 = (bp * 16 + r * 2 + jj) ^ bp;
    *(float4*)&gpart[kq * 520 + col4 * 4] = v;
  }
  __syncthreads();

  if (tid < 128) {
    const int b = tid >> 1, j2 = tid & 1;
    const int rbp = b >> 3, rr = b & 7;
    const int col4 = (rbp * 16 + rr * 2 + j2) ^ rbp;
    float4 gq = {0.f, 0.f, 0.f, 0.f};
    #pragma unroll
    for (int q = 0; q < 16; ++q) {
      float4 p = *(const float4*)&gpart[q * 520 + col4 * 4];
      gq.x += p.x; gq.y += p.y; gq.z += p.z; gq.w += p.w;
    }
    const int j = j0 + j2;
    float gI = gq.x + bias2[j2 * 4 + 0];
    float gF = gq.y + bias2[j2 * 4 + 1];
    float gG = gq.z + bias2[j2 * 4 + 2];
    float gO = gq.w + bias2[j2 * 4 + 3];

    float cp = creg;
    float si = 1.f / (1.f + expf(-gI));
    float sf = 1.f / (1.f + expf(-gF));
    float so = 1.f / (1.f + expf(-gO));
    float cn = sf * cp + si * tanhf(gG);
    float hn = so * tanhf(cn);
    creg = cn;
    float* hnx = ws + (LAYER ? OFF_H1 : OFF_H0) + ((ts + 1) & 1) * BH;
    st_coh(hnx + b * Hn + j, hn);
    if (LAYER == 0) {
      st_coh(ws + OFF_RING + tsb * BH + b * Hn + j, hn);
      if (ts == Tn - 1) {
        out[OUT_HN + b * Hn + j] = hn;                 // h_n[0]
        out[OUT_HN + 2 * BH + b * Hn + j] = cn;        // c_n[0]
      }
    } else {
      out[b * (Tn * Hn) + ts * Hn + j] = hn;           // output[b][ts][j]
      if (ts == Tn - 1) {
        out[OUT_HN + BH + b * Hn + j] = hn;            // h_n[1]
        out[OUT_HN + 3 * BH + b * Hn + j] = cn;        // c_n[1]
      }
    }
  }
}

__global__ __launch_bounds__(256) void bayes_lstm_persist(
    const float* __restrict__ x,
    const float* __restrict__ wihmu0, const float* __restrict__ whhmu0,
    const float* __restrict__ bihmu0, const float* __restrict__ bhhmu0,
    const float* __restrict__ wihmu1, const float* __restrict__ whhmu1,
    const float* __restrict__ bihmu1, const float* __restrict__ bhhmu1,
    float* __restrict__ ws, float* __restrict__ out)
{
  __shared__ __align__(16) char pool[POOL_BYTES];
  const int tid = threadIdx.x, bid = blockIdx.x;
  const int layer = bid >> 7, j0 = (bid & 127) * 2;
  float* wbuf  = (float*)(pool + WBUF_OFF);
  float* bias2 = (float*)(pool + BIAS_OFF);
  u32* slots = (u32*)(ws + OFF_SLOTS);
  u32* go    = (u32*)(ws + OFF_GO);
  float creg = 0.f;                  // block-private cell state (b=tid>>1, j=j0+(tid&1))

  // prefetch stage-0 weights (only L0 works at stage 0)
  if (layer == 0)
    sample_weights<0>(wihmu0, whhmu0, bihmu0, bhhmu0, ws, wbuf, bias2, 0, j0, tid);
  __syncthreads();

  for (int t = 0; t <= Tn; ++t) {
    if (layer == 0) {
      if (t < Tn) step_body<0>(x, ws, out, t, pool, creg);
    } else {
      if (t >= 1) step_body<1>(x, ws, out, t, pool, creg);
    }
    if (t == Tn) break;

    // ---- barrier: syncthreads drains each wave's stores (vmcnt0) before
    // ---- the arrival flag; compiler barriers pin post-spin load order.
    __syncthreads();
    if (tid == 0) st_flag(slots + bid * 32, (u32)(t + 1));

    if (bid == 0) {                  // master (layer-0 block, short step)
      u32* myslot = slots + tid * 32;
      while (ld_flag(myslot) < (u32)(t + 1))
        __builtin_amdgcn_s_sleep(1);
      asm volatile("" ::: "memory");   // no load may hoist above the gather
      __syncthreads();
      if (tid == 0) st_flag(go, (u32)(t + 1));
      // sample own next weights AFTER go (overlaps others' staging)
      sample_weights<0>(wihmu0, whhmu0, bihmu0, bhhmu0, ws, wbuf, bias2,
                        t + 1, j0, tid);
    } else {
      // sample next-stage weights while the barrier resolves
      if (layer == 0)
        sample_weights<0>(wihmu0, whhmu0, bihmu0, bhhmu0, ws, wbuf, bias2,
                          t + 1, j0, tid);
      else
        sample_weights<1>(wihmu1, whhmu1, bihmu1, bhhmu1, ws, wbuf, bias2,
                          t, j0, tid);
      if (tid == 0) {
        while (ld_flag(go) < (u32)(t + 1))
          __builtin_amdgcn_s_sleep(1);
      }
      asm volatile("" ::: "memory");   // no load may hoist above the go-poll
    }
    __syncthreads();
  }
}

__global__ __launch_bounds__(256) void bayes_lstm_prologue(
    const float* __restrict__ wihlv0, const float* __restrict__ whhlv0,
    const float* __restrict__ bihlv0, const float* __restrict__ bhhlv0,
    const float* __restrict__ wihlv1, const float* __restrict__ whhlv1,
    const float* __restrict__ bihlv1, const float* __restrict__ bhhlv1,
    float* __restrict__ ws)
{
  const int gt = blockIdx.x * 256 + threadIdx.x;
  const int stride = gridDim.x * 256;
  for (int i = gt; i < 65536; i += stride)
    ws[OFF_ELV_WIH0 + i] = expf(0.5f * wihlv0[i]);
  for (int i = gt; i < 262144; i += stride) {
    ws[OFF_ELV_WHH0 + i] = expf(0.5f * whhlv0[i]);
    ws[OFF_ELV_WIH1 + i] = expf(0.5f * wihlv1[i]);
    ws[OFF_ELV_WHH1 + i] = expf(0.5f * whhlv1[i]);
  }
  for (int i = gt; i < 1024; i += stride) {
    ws[OFF_ELV_B + i]        = expf(0.5f * bihlv0[i]);
    ws[OFF_ELV_B + 1024 + i] = expf(0.5f * bhhlv0[i]);
    ws[OFF_ELV_B + 2048 + i] = expf(0.5f * bihlv1[i]);
    ws[OFF_ELV_B + 3072 + i] = expf(0.5f * bhhlv1[i]);
  }
  // zero h/ring state COHERENTLY (consumers read via sc1 at L3)
  for (int i = gt; i < STATE_FLOATS; i += stride)
    st_coh(ws + OFF_RING + i, 0.f);
  for (int i = gt; i < 256 * 32 + 32; i += stride)
    st_flag((u32*)(ws + OFF_SLOTS) + i, 0u);  // reset barrier slots + go
  // threefry key table: (layer, ts) -> {kw, ku, kbi, kbh}
  if (gt < 2 * Tn) {
    int l = gt >> 7, ts = gt & 127;
    KP lk  = tf(0u, 42u, 0u, (u32)l);       // fold_in(key(42), l)
    KP kt  = tf(lk.a, lk.b, 0u, (u32)ts);   // split(layer_key, T)[ts]
    KP kw  = tf(kt.a, kt.b, 0u, 0u);
    KP ku  = tf(kt.a, kt.b, 0u, 1u);
    KP kbi = tf(kt.a, kt.b, 0u, 2u);
    KP kbh = tf(kt.a, kt.b, 0u, 3u);
    u32* kp = (u32*)(ws + OFF_KEYS) + gt * 8;
    kp[0] = kw.a;  kp[1] = kw.b;  kp[2] = ku.a;  kp[3] = ku.b;
    kp[4] = kbi.a; kp[5] = kbi.b; kp[6] = kbh.a; kp[7] = kbh.b;
  }
}

extern "C" void kernel_launch(void* const* d_in, const int* in_sizes, int n_in,
                              void* d_out, int out_size, void* d_ws, size_t ws_size,
                              hipStream_t stream) {
  (void)in_sizes; (void)n_in; (void)out_size;
  if (ws_size < (size_t)WS_FLOATS * sizeof(float)) return;  // need ~3.87 MiB

  const float* x      = (const float*)d_in[0];
  const float* wihmu0 = (const float*)d_in[1];
  const float* wihlv0 = (const float*)d_in[2];
  const float* whhmu0 = (const float*)d_in[3];
  const float* whhlv0 = (const float*)d_in[4];
  const float* bihmu0 = (const float*)d_in[5];
  const float* bihlv0 = (const float*)d_in[6];
  const float* bhhmu0 = (const float*)d_in[7];
  const float* bhhlv0 = (const float*)d_in[8];
  const float* wihmu1 = (const float*)d_in[9];
  const float* wihlv1 = (const float*)d_in[10];
  const float* whhmu1 = (const float*)d_in[11];
  const float* whhlv1 = (const float*)d_in[12];
  const float* bihmu1 = (const float*)d_in[13];
  const float* bihlv1 = (const float*)d_in[14];
  const float* bhhmu1 = (const float*)d_in[15];
  const float* bhhlv1 = (const float*)d_in[16];
  float* ws  = (float*)d_ws;
  float* out = (float*)d_out;

  bayes_lstm_prologue<<<dim3(256), dim3(256), 0, stream>>>(
      wihlv0, whhlv0, bihlv0, bhhlv0, wihlv1, whhlv1, bihlv1, bhhlv1, ws);

  bayes_lstm_persist<<<dim3(256), dim3(256), 0, stream>>>(
      x, wihmu0, whhmu0, bihmu0, bhhmu0,
      wihmu1, whhmu1, bihmu1, bhhmu1, ws, out);
}

// Round 8
// 1947.767 us; speedup vs baseline: 3.2081x; 1.2900x over previous
//
#include <hip/hip_runtime.h>
#include <stdint.h>

// BayesLSTM R7: R6 + (1) asm-opaque global_load_dwordx4 sc1 staging with
// counted vmcnt waits -- prefetched chunks survive __syncthreads (compiler
// can't see them, so it doesn't drain vmcnt for them); (2) float4 coherent
// loads (half the issue count); (3) master samples BEFORE gathering;
// (4) ring buffer removed -- L1 reads L0's h double-buffer directly.

typedef unsigned int u32;
typedef unsigned long long u64;
typedef float f32x4 __attribute__((ext_vector_type(4)));

#define Bn 64
#define Tn 128
#define INn 64
#define Hn 256
#define Gn 1024
#define BH (Bn * Hn)

#define OFF_ELV_WIH0 0
#define OFF_ELV_WHH0 65536
#define OFF_ELV_WIH1 327680
#define OFF_ELV_WHH1 589824
#define OFF_ELV_B    851968            // bih0,bhh0,bih1,bhh1 (4*1024)
#define OFF_H0       856064            // 2 x BH double buffer
#define OFF_H1       (OFF_H0 + 2 * BH)
#define OFF_KEYS     (OFF_H1 + 2 * BH)       // 2*128*8 u32 key table
#define OFF_SLOTS    (OFF_KEYS + 2 * Tn * 8) // 256 slots x 32 u32 (128B apart)
#define OFF_GO       (OFF_SLOTS + 256 * 32)
#define WS_FLOATS    (OFF_GO + 32)
#define STATE_FLOATS (OFF_KEYS - OFF_H0)     // h0+h1 = 4*BH
#define OUT_HN       (Bn * Tn * Hn)

struct KP { u32 a, b; };

// ---- coherent (agent-scope, relaxed) access helpers -------------------
__device__ __forceinline__ void st_coh(float* p, float v) {
  __hip_atomic_store(p, v, __ATOMIC_RELAXED, __HIP_MEMORY_SCOPE_AGENT);
}
__device__ __forceinline__ u32 ld_flag(const u32* p) {
  return __hip_atomic_load(p, __ATOMIC_RELAXED, __HIP_MEMORY_SCOPE_AGENT);
}
__device__ __forceinline__ void st_flag(u32* p, u32 v) {
  __hip_atomic_store(p, v, __ATOMIC_RELAXED, __HIP_MEMORY_SCOPE_AGENT);
}

// Threefry-2x32, 20 rounds — matches jax/_src/prng.py exactly.
__device__ __forceinline__ KP tf(u32 k0, u32 k1, u32 x0, u32 x1) {
  u32 ks2 = k0 ^ k1 ^ 0x1BD11BDAu;
  x0 += k0; x1 += k1;
#define TFR(r) { x0 += x1; x1 = (x1 << (r)) | (x1 >> (32 - (r))); x1 ^= x0; }
  TFR(13) TFR(15) TFR(26) TFR(6)
  x0 += k1;  x1 += ks2 + 1u;
  TFR(17) TFR(29) TFR(16) TFR(24)
  x0 += ks2; x1 += k0 + 2u;
  TFR(13) TFR(15) TFR(26) TFR(6)
  x0 += k0;  x1 += k1 + 3u;
  TFR(17) TFR(29) TFR(16) TFR(24)
  x0 += k1;  x1 += ks2 + 4u;
  TFR(13) TFR(15) TFR(26) TFR(6)
  x0 += ks2; x1 += k0 + 5u;
#undef TFR
  KP o; o.a = x0; o.b = x1; return o;
}

// bits -> N(0,1) matching jax.random.normal f32 (erfinv = XLA/Giles poly).
__device__ __forceinline__ float n01(u32 bits) {
  float f = __uint_as_float((bits >> 9) | 0x3f800000u) - 1.0f;
  float u = fmaxf(-0.99999994f, f * 2.0f - 0.99999994f);
  float w = -log1pf(-u * u);
  float p;
  if (w < 5.0f) {
    float z = w - 2.5f;
    p = 2.81022636e-08f;
    p = 3.43273939e-07f  + p * z;
    p = -3.5233877e-06f  + p * z;
    p = -4.39150654e-06f + p * z;
    p = 0.00021858087f   + p * z;
    p = -0.00125372503f  + p * z;
    p = -0.00417768164f  + p * z;
    p = 0.246640727f     + p * z;
    p = 1.50140941f      + p * z;
  } else {
    float z = sqrtf(w) - 3.0f;
    p = -0.000200214257f;
    p = 0.000100950558f  + p * z;
    p = 0.00134934322f   + p * z;
    p = -0.00367342844f  + p * z;
    p = 0.00573950773f   + p * z;
    p = -0.0076224613f   + p * z;
    p = 0.00943887047f   + p * z;
    p = 1.00167406f      + p * z;
    p = 2.83297682f      + p * z;
  }
  return 1.41421356237f * (p * u);
}

// LDS pool carve (bytes): [wbuf 8x516 f32 =16512 | PERSISTS across barrier]
// [inb 2x64x68 f32 =34816 at 16512] ; gpart 16x520 f32 =33280 ALIASES inb.
// bias2 (8 f32) at 51328.
#define POOL_BYTES 51360
#define WBUF_OFF   0
#define INB_OFF    16512
#define BIAS_OFF   51328

// Sample weights + bias for (LAYER, ts) into wbuf/bias2. Depends only on
// key table + mu + elv (all L2-warm plain loads) — runs under barrier wait.
template<int LAYER>
__device__ __forceinline__ void sample_weights(
    const float* __restrict__ wihmu, const float* __restrict__ whhmu,
    const float* __restrict__ bihmu, const float* __restrict__ bhhmu,
    const float* __restrict__ ws, float* __restrict__ wbuf,
    float* __restrict__ bias2, int ts, int j0, int tid)
{
  constexpr int Kin  = LAYER ? Hn : INn;
  constexpr int Ktot = Kin + Hn;
  if (ts >= Tn) return;
  const u32* kp = (const u32*)(ws + OFF_KEYS) + (LAYER * Tn + ts) * 8;
  const float* elv_ih  = ws + (LAYER ? OFF_ELV_WIH1 : OFF_ELV_WIH0);
  const float* elv_hh  = ws + (LAYER ? OFF_ELV_WHH1 : OFF_ELV_WHH0);
  const float* belv_ih = ws + OFF_ELV_B + LAYER * 2048;
  const float* belv_hh = belv_ih + 1024;

  const u32 kwa = kp[0], kwb = kp[1], kua = kp[2], kub = kp[3];
  #pragma unroll
  for (int it = 0; it < (Ktot + 255) / 256; ++it) {
    int k = tid + it * 256;
    if (k < Ktot) {
      bool iswih = k < Kin;
      u32 ka = iswih ? kwa : kua, kb = iswih ? kwb : kub;
      const float* mup  = iswih ? wihmu  : whhmu;
      const float* elvp = iswih ? elv_ih : elv_hh;
      int kk = iswih ? k : k - Kin;
      int kstride = iswih ? Kin : Hn;
      #pragma unroll
      for (int gi = 0; gi < 8; ++gi) {           // gi = jj*4 + s
        int g = (gi & 3) * Hn + j0 + (gi >> 2);
        int i = g * kstride + kk;
        KP r = tf(ka, kb, 0u, (u32)i);
        wbuf[gi * 516 + k] = mup[i] + elvp[i] * n01(r.a ^ r.b);
      }
    }
  }
  if (tid < 8) {
    int g = (tid & 3) * Hn + j0 + (tid >> 2);
    KP rb = tf(kp[4], kp[5], 0u, (u32)g);
    KP rh = tf(kp[6], kp[7], 0u, (u32)g);
    bias2[tid] = bihmu[g] + belv_ih[g] * n01(rb.a ^ rb.b)
               + bhhmu[g] + belv_hh[g] * n01(rh.a ^ rh.b);
  }
}

// Step body. Staging loads are ASM-OPAQUE (global_load_dwordx4, sc1 for h,
// plain for x) with counted vmcnt waits — so per-chunk __syncthreads does
// NOT drain them (compiler can't see them) and a 2-chunk-deep prefetch
// pipeline survives the barriers. ALL loads in this window go through asm
// so the vmcnt arithmetic is exact.
template<int LAYER>
__device__ void step_body(
    const float* __restrict__ x,
    float* __restrict__ ws, float* __restrict__ out, int t, char* pool,
    float& creg)
{
  constexpr int Kin  = LAYER ? Hn : INn;
  constexpr int Ktot = Kin + Hn;      // 512 or 320
  constexpr int nch  = Ktot / 64;     // 8 or 5
  const int tid = threadIdx.x;
  const int lb  = blockIdx.x & 127;
  const int j0  = lb * 2;
  const int ts  = LAYER ? (t - 1) : t;

  float* wbuf  = (float*)(pool + WBUF_OFF);   // [8][516] (pre-filled)
  float* inb   = (float*)(pool + INB_OFF);    // [2][64][68]
  float* gpart = (float*)(pool + INB_OFF);    // [16][520], aliases inb
  float* bias2 = (float*)(pool + BIAS_OFF);   // [8]   (pre-filled)

  // h buffers: own-layer prev h at slot ts&1; L1's "x" = L0 h at slot (ts+1)&1
  const float* hprev = ws + (LAYER ? OFF_H1 : OFF_H0) + (ts & 1) * BH;
  const float* h0in  = ws + OFF_H0 + ((ts + 1) & 1) * BH;   // L1 only

  // ---- asm staging: f = tid+256m -> row b=f>>4, quad q4=(f&15)*4 --------
  f32x4 pfA[4], pfB[4];
  auto issue = [&](int c, f32x4* pf) {
    #pragma unroll
    for (int m = 0; m < 4; ++m) {
      int f = tid + 256 * m, b = f >> 4, q4 = (f & 15) * 4;
      if (LAYER == 0) {
        if (c == 0) {
          const float* p = x + (b * Tn + ts) * INn + q4;
          asm volatile("global_load_dwordx4 %0, %1, off"
                       : "=v"(pf[m]) : "v"(p) : "memory");
        } else {
          const float* p = hprev + b * Hn + (c - 1) * 64 + q4;
          asm volatile("global_load_dwordx4 %0, %1, off sc1"
                       : "=v"(pf[m]) : "v"(p) : "memory");
        }
      } else {
        const float* p = (c < 4) ? (h0in + b * Hn + c * 64 + q4)
                                 : (hprev + b * Hn + (c - 4) * 64 + q4);
        asm volatile("global_load_dwordx4 %0, %1, off sc1"
                     : "=v"(pf[m]) : "v"(p) : "memory");
      }
    }
  };
  auto writeb = [&](int c, f32x4* pf) {
    #pragma unroll
    for (int m = 0; m < 4; ++m) {
      int f = tid + 256 * m, b = f >> 4, seg = f & 15;
      int col = 4 * (seg ^ ((b >> 3) & 7));
      *(f32x4*)&inb[(((c & 1) << 6) + b) * 68 + col] = pf[m];
    }
  };

  // ---- prologue: 2-deep prefetch, write chunk 0 -------------------------
  issue(0, pfA);
  if (nch > 1) issue(1, pfB);
  if (nch > 1) asm volatile("s_waitcnt vmcnt(4)" ::: "memory");
  else         asm volatile("s_waitcnt vmcnt(0)" ::: "memory");
  __builtin_amdgcn_sched_barrier(0);
  writeb(0, pfA);
  __syncthreads();

  // ---- chunked FMA, k-split 16, per-thread 8b x 4s tile -----------------
  const int kq = tid >> 4;          // 0..15 : k-quad within chunk
  const int bp = (tid >> 1) & 7;    // 0..7  : batch group (8 rows)
  const int jj = tid & 1;           // 0..1  : which j column
  const int colq = 4 * (kq ^ bp);   // swizzled inb column (holds quad kq)

  float acc[8][4];
  #pragma unroll
  for (int r = 0; r < 8; ++r)
    acc[r][0] = acc[r][1] = acc[r][2] = acc[r][3] = 0.f;

  #pragma unroll
  for (int c = 0; c < nch; ++c) {
    f32x4* cur = (c & 1) ? pfB : pfA;   // freed slot -> receives chunk c+2
    f32x4* nxt = (c & 1) ? pfA : pfB;   // holds chunk c+1
    if (c + 2 < nch) issue(c + 2, cur);
    float4 w4[4];
    #pragma unroll
    for (int s = 0; s < 4; ++s)
      w4[s] = *(const float4*)&wbuf[(jj * 4 + s) * 516 + c * 64 + kq * 4];
    #pragma unroll
    for (int r = 0; r < 8; ++r) {
      float4 in4 = *(const float4*)&inb[(((c & 1) << 6) + bp * 8 + r) * 68 + colq];
      #pragma unroll
      for (int s = 0; s < 4; ++s)
        acc[r][s] += in4.x * w4[s].x + in4.y * w4[s].y
                   + in4.z * w4[s].z + in4.w * w4[s].w;
    }
    if (c + 1 < nch) {
      if (c + 2 < nch) asm volatile("s_waitcnt vmcnt(4)" ::: "memory");
      else             asm volatile("s_waitcnt vmcnt(0)" ::: "memory");
      __builtin_amdgcn_sched_barrier(0);
      writeb(c + 1, nxt);
    }
    __syncthreads();
  }

  // ---- k-partials to LDS (bp-swizzled), reduce, activate ----------------
  #pragma unroll
  for (int r = 0; r < 8; ++r) {
    float4 v = {acc[r][0], acc[r][1], acc[r][2], acc[r][3]};
    int col4 = (bp * 16 + r * 2 + jj) ^ bp;
    *(float4*)&gpart[kq * 520 + col4 * 4] = v;
  }
  __syncthreads();

  if (tid < 128) {
    const int b = tid >> 1, j2 = tid & 1;
    const int rbp = b >> 3, rr = b & 7;
    const int col4 = (rbp * 16 + rr * 2 + j2) ^ rbp;
    float4 gq = {0.f, 0.f, 0.f, 0.f};
    #pragma unroll
    for (int q = 0; q < 16; ++q) {
      float4 p = *(const float4*)&gpart[q * 520 + col4 * 4];
      gq.x += p.x; gq.y += p.y; gq.z += p.z; gq.w += p.w;
    }
    const int j = j0 + j2;
    float gI = gq.x + bias2[j2 * 4 + 0];
    float gF = gq.y + bias2[j2 * 4 + 1];
    float gG = gq.z + bias2[j2 * 4 + 2];
    float gO = gq.w + bias2[j2 * 4 + 3];

    float cp = creg;
    float si = 1.f / (1.f + expf(-gI));
    float sf = 1.f / (1.f + expf(-gF));
    float so = 1.f / (1.f + expf(-gO));
    float cn = sf * cp + si * tanhf(gG);
    float hn = so * tanhf(cn);
    creg = cn;
    float* hnx = ws + (LAYER ? OFF_H1 : OFF_H0) + ((ts + 1) & 1) * BH;
    st_coh(hnx + b * Hn + j, hn);
    if (LAYER == 0) {
      if (ts == Tn - 1) {
        out[OUT_HN + b * Hn + j] = hn;                 // h_n[0]
        out[OUT_HN + 2 * BH + b * Hn + j] = cn;        // c_n[0]
      }
    } else {
      out[b * (Tn * Hn) + ts * Hn + j] = hn;           // output[b][ts][j]
      if (ts == Tn - 1) {
        out[OUT_HN + BH + b * Hn + j] = hn;            // h_n[1]
        out[OUT_HN + 3 * BH + b * Hn + j] = cn;        // c_n[1]
      }
    }
  }
}

__global__ __launch_bounds__(256) void bayes_lstm_persist(
    const float* __restrict__ x,
    const float* __restrict__ wihmu0, const float* __restrict__ whhmu0,
    const float* __restrict__ bihmu0, const float* __restrict__ bhhmu0,
    const float* __restrict__ wihmu1, const float* __restrict__ whhmu1,
    const float* __restrict__ bihmu1, const float* __restrict__ bhhmu1,
    float* __restrict__ ws, float* __restrict__ out)
{
  __shared__ __align__(16) char pool[POOL_BYTES];
  const int tid = threadIdx.x, bid = blockIdx.x;
  const int layer = bid >> 7, j0 = (bid & 127) * 2;
  float* wbuf  = (float*)(pool + WBUF_OFF);
  float* bias2 = (float*)(pool + BIAS_OFF);
  u32* slots = (u32*)(ws + OFF_SLOTS);
  u32* go    = (u32*)(ws + OFF_GO);
  float creg = 0.f;                  // block-private cell state

  // prefetch stage-0 weights (only L0 works at stage 0)
  if (layer == 0)
    sample_weights<0>(wihmu0, whhmu0, bihmu0, bhhmu0, ws, wbuf, bias2, 0, j0, tid);
  __syncthreads();

  for (int t = 0; t <= Tn; ++t) {
    if (layer == 0) {
      if (t < Tn) step_body<0>(x, ws, out, t, pool, creg);
    } else {
      if (t >= 1) step_body<1>(x, ws, out, t, pool, creg);
    }
    if (t == Tn) break;

    // ---- barrier: syncthreads drains this block's h-stores before the
    // ---- arrival flag; sampling hidden under the wait (master included).
    __syncthreads();
    if (tid == 0) st_flag(slots + bid * 32, (u32)(t + 1));

    // sample next-stage weights while the barrier resolves
    if (layer == 0)
      sample_weights<0>(wihmu0, whhmu0, bihmu0, bhhmu0, ws, wbuf, bias2,
                        t + 1, j0, tid);
    else
      sample_weights<1>(wihmu1, whhmu1, bihmu1, bhhmu1, ws, wbuf, bias2,
                        t, j0, tid);

    if (bid == 0) {                  // master gathers AFTER sampling
      u32* myslot = slots + tid * 32;
      while (ld_flag(myslot) < (u32)(t + 1))
        __builtin_amdgcn_s_sleep(1);
      asm volatile("" ::: "memory");   // no load may hoist above the gather
      __syncthreads();
      if (tid == 0) st_flag(go, (u32)(t + 1));
    } else {
      if (tid == 0) {
        while (ld_flag(go) < (u32)(t + 1))
          __builtin_amdgcn_s_sleep(1);
      }
      asm volatile("" ::: "memory");   // no load may hoist above the go-poll
    }
    __syncthreads();
  }
}

__global__ __launch_bounds__(256) void bayes_lstm_prologue(
    const float* __restrict__ wihlv0, const float* __restrict__ whhlv0,
    const float* __restrict__ bihlv0, const float* __restrict__ bhhlv0,
    const float* __restrict__ wihlv1, const float* __restrict__ whhlv1,
    const float* __restrict__ bihlv1, const float* __restrict__ bhhlv1,
    float* __restrict__ ws)
{
  const int gt = blockIdx.x * 256 + threadIdx.x;
  const int stride = gridDim.x * 256;
  for (int i = gt; i < 65536; i += stride)
    ws[OFF_ELV_WIH0 + i] = expf(0.5f * wihlv0[i]);
  for (int i = gt; i < 262144; i += stride) {
    ws[OFF_ELV_WHH0 + i] = expf(0.5f * whhlv0[i]);
    ws[OFF_ELV_WIH1 + i] = expf(0.5f * wihlv1[i]);
    ws[OFF_ELV_WHH1 + i] = expf(0.5f * whhlv1[i]);
  }
  for (int i = gt; i < 1024; i += stride) {
    ws[OFF_ELV_B + i]        = expf(0.5f * bihlv0[i]);
    ws[OFF_ELV_B + 1024 + i] = expf(0.5f * bhhlv0[i]);
    ws[OFF_ELV_B + 2048 + i] = expf(0.5f * bihlv1[i]);
    ws[OFF_ELV_B + 3072 + i] = expf(0.5f * bhhlv1[i]);
  }
  // zero h0/h1 state COHERENTLY (consumers read via sc1 at L3)
  for (int i = gt; i < STATE_FLOATS; i += stride)
    st_coh(ws + OFF_H0 + i, 0.f);
  for (int i = gt; i < 256 * 32 + 32; i += stride)
    st_flag((u32*)(ws + OFF_SLOTS) + i, 0u);  // reset barrier slots + go
  // threefry key table: (layer, ts) -> {kw, ku, kbi, kbh}
  if (gt < 2 * Tn) {
    int l = gt >> 7, ts = gt & 127;
    KP lk  = tf(0u, 42u, 0u, (u32)l);       // fold_in(key(42), l)
    KP kt  = tf(lk.a, lk.b, 0u, (u32)ts);   // split(layer_key, T)[ts]
    KP kw  = tf(kt.a, kt.b, 0u, 0u);
    KP ku  = tf(kt.a, kt.b, 0u, 1u);
    KP kbi = tf(kt.a, kt.b, 0u, 2u);
    KP kbh = tf(kt.a, kt.b, 0u, 3u);
    u32* kp = (u32*)(ws + OFF_KEYS) + gt * 8;
    kp[0] = kw.a;  kp[1] = kw.b;  kp[2] = ku.a;  kp[3] = ku.b;
    kp[4] = kbi.a; kp[5] = kbi.b; kp[6] = kbh.a; kp[7] = kbh.b;
  }
}

extern "C" void kernel_launch(void* const* d_in, const int* in_sizes, int n_in,
                              void* d_out, int out_size, void* d_ws, size_t ws_size,
                              hipStream_t stream) {
  (void)in_sizes; (void)n_in; (void)out_size;
  if (ws_size < (size_t)WS_FLOATS * sizeof(float)) return;  // need ~3.6 MiB

  const float* x      = (const float*)d_in[0];
  const float* wihmu0 = (const float*)d_in[1];
  const float* wihlv0 = (const float*)d_in[2];
  const float* whhmu0 = (const float*)d_in[3];
  const float* whhlv0 = (const float*)d_in[4];
  const float* bihmu0 = (const float*)d_in[5];
  const float* bihlv0 = (const float*)d_in[6];
  const float* bhhmu0 = (const float*)d_in[7];
  const float* bhhlv0 = (const float*)d_in[8];
  const float* wihmu1 = (const float*)d_in[9];
  const float* wihlv1 = (const float*)d_in[10];
  const float* whhmu1 = (const float*)d_in[11];
  const float* whhlv1 = (const float*)d_in[12];
  const float* bihmu1 = (const float*)d_in[13];
  const float* bihlv1 = (const float*)d_in[14];
  const float* bhhmu1 = (const float*)d_in[15];
  const float* bhhlv1 = (const float*)d_in[16];
  float* ws  = (float*)d_ws;
  float* out = (float*)d_out;

  bayes_lstm_prologue<<<dim3(256), dim3(256), 0, stream>>>(
      wihlv0, whhlv0, bihlv0, bhhlv0, wihlv1, whhlv1, bihlv1, bhhlv1, ws);

  bayes_lstm_persist<<<dim3(256), dim3(256), 0, stream>>>(
      x, wihmu0, whhmu0, bihmu0, bhhmu0,
      wihmu1, whhmu1, bihmu1, bhhmu1, ws, out);
}